// Round 3
// baseline (279.430 us; speedup 1.0000x reference)
//
#include <hip/hip_runtime.h>

// Problem constants from the reference: B,C,H,W = 32,1,720,1280
constexpr int Bn = 32;
constexpr int Hn = 720;
constexpr int Wn = 1280;
constexpr int RY = 8;                 // output rows per block
constexpr int MAXR = RY + 2;          // max source rows needed (10)

// vertical coordinate chain — must be the exact same op order everywhere
__device__ __forceinline__ void vcoord(int y, int& y0, float& wy1) {
    float gy  = (((float)y - (float)(Hn - 1) * 0.5f) / (float)(Hn - 1)) * 2.0f;
    float iy  = ((gy + 1.0f) * (float)Hn - 1.0f) * 0.5f;
    float fy0 = floorf(iy);
    wy1 = iy - fy0;
    y0  = (int)fy0;
}

// One block = 8 consecutive output rows of one batch image.
// 512 threads: wave w (= tid/64) owns output row Y+w; lane handles 4 px x 5 chunks.
// Stage the <=10 needed source rows in LDS with one barrier, then compute
// barrier-free.
__global__ __launch_bounds__(512) void warp_kernel(
    const float* __restrict__ img,
    const float* __restrict__ disp,
    float* __restrict__ out)
{
    __shared__ float srow[MAXR * Wn];            // 51200 B

    const int hw   = Hn * Wn;
    const int tile = blockIdx.x;                 // b * (Hn/RY) + ytile
    const int b    = tile / (Hn / RY);
    const int Y    = (tile - b * (Hn / RY)) * RY;
    const int tid  = threadIdx.x;

    // source-row range for output rows [Y, Y+RY-1]
    int y0_first, y0_last; float dum;
    vcoord(Y, y0_first, dum);
    vcoord(Y + RY - 1, y0_last, dum);
    const int lo = min(max(y0_first, 0), Hn - 1);
    const int hi = min(max(y0_last + 1, 0), Hn - 1);
    const int nr = hi - lo + 1;                  // <= MAXR

    const float* __restrict__ imb = img + (long long)b * hw;

    // ---- stage nr source rows into LDS (coalesced float4) ----
    {
        const int nchunk = nr * (Wn / 4);        // float4 chunks total
        float4* dst = reinterpret_cast<float4*>(srow);
        for (int j = tid; j < nchunk; j += 512) {
            int r  = j / (Wn / 4);
            int cx = j - r * (Wn / 4);
            dst[j] = reinterpret_cast<const float4*>(imb + (long long)(lo + r) * Wn)[cx];
        }
    }
    __syncthreads();

    // ---- per-wave output row ----
    const int w    = tid >> 6;                   // 0..7
    const int lane = tid & 63;
    const int y    = Y + w;

    int y0; float wy1;
    vcoord(y, y0, wy1);
    const float wy0 = 1.0f - wy1;
    const int   y1  = y0 + 1;
    const float my0 = ((y0 >= 0) && (y0 < Hn)) ? 1.0f : 0.0f;
    const float my1 = ((y1 >= 0) && (y1 < Hn)) ? 1.0f : 0.0f;
    const int   y0c = min(max(y0, 0), Hn - 1);
    const int   y1c = min(max(y1, 0), Hn - 1);

    const float* __restrict__ r0 = srow + (y0c - lo) * Wn;
    const float* __restrict__ r1 = srow + (y1c - lo) * Wn;

    const long long rowbase = (long long)(b * Hn + y) * Wn;

#pragma unroll
    for (int k = 0; k < 5; ++k) {
        const int xpix = 4 * (lane + 64 * k);    // 0..1276, step 4
        const float4 d4 = *reinterpret_cast<const float4*>(disp + rowbase + xpix);
        float dv[4] = {d4.x, d4.y, d4.z, d4.w};
        float res[4];

#pragma unroll
        for (int i = 0; i < 4; ++i) {
            float xf  = (float)(xpix + i);
            float gx  = ((xf - dv[i] - (float)(Wn - 1) * 0.5f) / (float)(Wn - 1)) * 2.0f;
            float ix  = ((gx + 1.0f) * (float)Wn - 1.0f) * 0.5f;
            float fx0 = floorf(ix);
            float wx1 = ix - fx0;
            float wx0 = 1.0f - wx1;
            int   x0  = (int)fx0;
            int   x1  = x0 + 1;
            float mx0 = ((x0 >= 0) && (x0 < Wn)) ? 1.0f : 0.0f;
            float mx1 = ((x1 >= 0) && (x1 < Wn)) ? 1.0f : 0.0f;
            int   x0c = min(max(x0, 0), Wn - 1);
            int   x1c = min(max(x1, 0), Wn - 1);

            float v00 = r0[x0c] * (my0 * mx0);
            float v01 = r0[x1c] * (my0 * mx1);
            float v10 = r1[x0c] * (my1 * mx0);
            float v11 = r1[x1c] * (my1 * mx1);

            res[i] = v00 * (wy0 * wx0) + v01 * (wy0 * wx1)
                   + v10 * (wy1 * wx0) + v11 * (wy1 * wx1);
        }

        float4 o4 = make_float4(res[0], res[1], res[2], res[3]);
        *reinterpret_cast<float4*>(out + rowbase + xpix) = o4;
    }
}

extern "C" void kernel_launch(void* const* d_in, const int* in_sizes, int n_in,
                              void* d_out, int out_size, void* d_ws, size_t ws_size,
                              hipStream_t stream) {
    const float* img  = (const float*)d_in[0];   // right_img [32,1,720,1280] fp32
    const float* disp = (const float*)d_in[1];   // disp      [32,1,720,1280] fp32
    float* out = (float*)d_out;                  // [32,1,720,1280] fp32

    const int grid  = Bn * (Hn / RY);   // 32 * 90 = 2880 blocks
    const int block = 512;              // 8 waves, one per output row

    warp_kernel<<<grid, block, 0, stream>>>(img, disp, out);
}